// Round 4
// baseline (1349.284 us; speedup 1.0000x reference)
//
#include <hip/hip_runtime.h>

// GCN 2-layer forward, fp32.
// Round-3 evidence: random 4B scatter in fill_kernel writes 294 MB HBM for a
// 25.6 MB payload (line-granularity amplification). Fix: partition edges into
// 128-node target buckets (LDS-staged binning, coalesced run flushes, 4B/edge
// packed payload), then aggregate per bucket in an LDS fp32 tile with
// ds_add_f32 — each output element written to HBM exactly once, bias/ReLU
// fused. Degree comes from a per-bucket histogram of the packed array.

#define WAVE 64
#define BNODES 128        // target nodes per bucket (7 bits local col)
#define NBMAX 1024        // max buckets supported (N <= 131072)
#define CHUNK 8192        // edges per partition block

// ---- bucket count: global histogram of col>>7 ----
__global__ void bucket_count_kernel(const int* __restrict__ col, int* __restrict__ gcnt,
                                    int E, int nb) {
    __shared__ int h[NBMAX];
    for (int i = threadIdx.x; i < nb; i += blockDim.x) h[i] = 0;
    __syncthreads();
    for (int e = blockIdx.x * blockDim.x + threadIdx.x; e < E; e += gridDim.x * blockDim.x)
        atomicAdd(&h[col[e] >> 7], 1);
    __syncthreads();
    for (int i = threadIdx.x; i < nb; i += blockDim.x)
        if (h[i]) atomicAdd(&gcnt[i], h[i]);
}

// ---- exclusive scan of bucket counts -> bucket_ptr[nb+1], init gcursor ----
__global__ void bucket_scan_kernel(const int* __restrict__ cnt, int* __restrict__ bptr,
                                   int* __restrict__ gcur, int nb) {
    int lane = threadIdx.x;  // single wave of 64
    int carry = 0;
    for (int base = 0; base < nb; base += WAVE) {
        int i = base + lane;
        int orig = (i < nb) ? cnt[i] : 0;
        int v = orig;
#pragma unroll
        for (int off = 1; off < WAVE; off <<= 1) {
            int t = __shfl_up(v, off, WAVE);
            if (lane >= off) v += t;
        }
        if (i < nb) { bptr[i] = carry + v - orig; gcur[i] = carry + v - orig; }
        carry += __shfl(v, WAVE - 1, WAVE);
    }
    if (lane == 0) bptr[nb] = carry;
}

// ---- partition: LDS-binned scatter of packed (src<<7 | local_col) ----
__global__ void __launch_bounds__(512)
partition_kernel(const int* __restrict__ row, const int* __restrict__ col,
                 int* __restrict__ gcursor, unsigned* __restrict__ packed,
                 int E, int nb) {
    __shared__ int hist[NBMAX], excl[NBMAX], cursor[NBMAX], baseoff[NBMAX];
    __shared__ unsigned stage[CHUNK];
    int chunk0 = blockIdx.x * CHUNK;
    int cn = E - chunk0; if (cn > CHUNK) cn = CHUNK;
    for (int i = threadIdx.x; i < nb; i += blockDim.x) hist[i] = 0;
    __syncthreads();
    // A: local histogram
    for (int i = threadIdx.x; i < cn; i += blockDim.x)
        atomicAdd(&hist[col[chunk0 + i] >> 7], 1);
    __syncthreads();
    // B: exclusive scan (wave 0)
    if (threadIdx.x < WAVE) {
        int lane = threadIdx.x, carry = 0;
        for (int base = 0; base < nb; base += WAVE) {
            int i = base + lane;
            int orig = (i < nb) ? hist[i] : 0;
            int v = orig;
#pragma unroll
            for (int off = 1; off < WAVE; off <<= 1) {
                int t = __shfl_up(v, off, WAVE);
                if (lane >= off) v += t;
            }
            if (i < nb) { excl[i] = carry + v - orig; cursor[i] = carry + v - orig; }
            carry += __shfl(v, WAVE - 1, WAVE);
        }
    }
    __syncthreads();
    // C: reserve global runs
    for (int b = threadIdx.x; b < nb; b += blockDim.x) {
        int c = hist[b];
        baseoff[b] = c ? atomicAdd(&gcursor[b], c) : 0;
    }
    __syncthreads();
    // D: stage packed values bucket-ordered in LDS
    for (int i = threadIdx.x; i < cn; i += blockDim.x) {
        int c = col[chunk0 + i], r = row[chunk0 + i];
        int b = c >> 7;
        int pos = atomicAdd(&cursor[b], 1);
        stage[pos] = ((unsigned)r << 7) | (unsigned)(c & (BNODES - 1));
    }
    __syncthreads();
    // E: coalesced run flush, one wave per bucket round-robin
    int wave = threadIdx.x >> 6, lane = threadIdx.x & 63, nw = blockDim.x >> 6;
    for (int b = wave; b < nb; b += nw) {
        int c = hist[b]; if (!c) continue;
        int s = excl[b], d = baseoff[b];
        for (int k = lane; k < c; k += WAVE) packed[d + k] = stage[s + k];
    }
}

// ---- per-bucket degree -> dinv ----
__global__ void bucket_deg_kernel(const int* __restrict__ bptr, const unsigned* __restrict__ packed,
                                  float* __restrict__ dinv, int n, int nb) {
    __shared__ int cnt[BNODES];
    int b = blockIdx.x;
    for (int i = threadIdx.x; i < BNODES; i += blockDim.x) cnt[i] = 0;
    __syncthreads();
    int start = bptr[b], end = bptr[b + 1];
    for (int k = start + threadIdx.x; k < end; k += blockDim.x)
        atomicAdd(&cnt[packed[k] & (BNODES - 1)], 1);
    __syncthreads();
    for (int i = threadIdx.x; i < BNODES; i += blockDim.x) {
        int node = b * BNODES + i;
        if (node < n) dinv[node] = cnt[i] ? rsqrtf((float)cnt[i]) : 0.f;
    }
}

// ---- dense: h[n,OUTC] = x[n,INC] @ W ----
template <int INC, int OUTC>
__global__ void dense_kernel(const float* __restrict__ x, const float* __restrict__ W,
                             float* __restrict__ h, int n) {
    __shared__ float Wl[INC * OUTC];
    for (int i = threadIdx.x; i < INC * OUTC; i += blockDim.x) Wl[i] = W[i];
    __syncthreads();
    const int npb  = blockDim.x / OUTC;
    const int j    = threadIdx.x % OUTC;
    const int slot = threadIdx.x / OUTC;
    for (int node = blockIdx.x * npb + slot; node < n; node += gridDim.x * npb) {
        const float4* xr = (const float4*)(x + (size_t)node * INC);
        float acc = 0.f;
#pragma unroll
        for (int k4 = 0; k4 < INC / 4; ++k4) {
            float4 v = xr[k4];
            acc = fmaf(v.x, Wl[(k4 * 4 + 0) * OUTC + j], acc);
            acc = fmaf(v.y, Wl[(k4 * 4 + 1) * OUTC + j], acc);
            acc = fmaf(v.z, Wl[(k4 * 4 + 2) * OUTC + j], acc);
            acc = fmaf(v.w, Wl[(k4 * 4 + 3) * OUTC + j], acc);
        }
        h[(size_t)node * OUTC + j] = acc;
    }
}

// ---- bucket aggregate: LDS fp32 tile, ds_add_f32, fused bias(/relu) ----
template <int C, bool RELU>
__global__ void __launch_bounds__(512)
bucket_agg_kernel(const int* __restrict__ bptr, const unsigned* __restrict__ packed,
                  const float* __restrict__ dinv, const float* __restrict__ h,
                  const float* __restrict__ bias, float* __restrict__ out,
                  int n, int nb) {
    __shared__ float acc[BNODES * C];
    __shared__ float dl[BNODES];
    __shared__ float bl[C];
    int b = blockIdx.x;
    int base_node = b * BNODES;
    for (int i = threadIdx.x; i < BNODES * C; i += blockDim.x) acc[i] = 0.f;
    for (int i = threadIdx.x; i < BNODES; i += blockDim.x) {
        int node = base_node + i;
        dl[i] = (node < n) ? dinv[node] : 0.f;
    }
    if (threadIdx.x < C) bl[threadIdx.x] = bias[threadIdx.x];
    __syncthreads();
    int start = bptr[b], end = bptr[b + 1];
    const int EPW = WAVE / C;                 // edges per wave-step
    int nwaves = blockDim.x >> 6;
    int wave = threadIdx.x >> 6;
    int lane = threadIdx.x & 63;
    int j  = lane & (C - 1);
    int eo = lane / C;
#pragma unroll 2
    for (int k = start + wave * EPW + eo; k < end; k += nwaves * EPW) {
        unsigned p = packed[k];
        int lc  = p & (BNODES - 1);
        int src = p >> 7;
        float w = dinv[src] * dl[lc];
        float v = h[(size_t)src * C + j] * w;
        atomicAdd(&acc[lc * C + j], v);
    }
    __syncthreads();
    for (int i = threadIdx.x; i < BNODES * C; i += blockDim.x) {
        int node = base_node + (i / C);
        if (node < n) {
            float v = acc[i] + bl[i & (C - 1)];
            if (RELU) v = v > 0.f ? v : 0.f;
            out[(size_t)base_node * C + i] = v;
        }
    }
}

__global__ void tail_kernel(float* __restrict__ out, int idx) {
    if (blockIdx.x == 0 && threadIdx.x == 0) out[idx] = 0.f;
}

extern "C" void kernel_launch(void* const* d_in, const int* in_sizes, int n_in,
                              void* d_out, int out_size, void* d_ws, size_t ws_size,
                              hipStream_t stream) {
    const float* x  = (const float*)d_in[0];
    const int*   ei = (const int*)d_in[1];    // harness converts int64 -> int32
    const float* W1 = (const float*)d_in[2];
    const float* b1 = (const float*)d_in[3];
    const float* W2 = (const float*)d_in[4];
    const float* b2 = (const float*)d_in[5];

    const int IN_C = 128, HID = 32, OC = 16;
    const int N = in_sizes[0] / IN_C;       // 100000
    const int E = in_sizes[1] / 2;          // 3200000
    const int* row = ei;
    const int* col = ei + E;
    const int NB = (N + BNODES - 1) / BNODES;   // 782

    char* base = (char*)d_ws;
    size_t off = 0;
    auto carve = [&](size_t bytes) -> char* {
        char* p = base + off;
        off = (off + bytes + 255) & ~(size_t)255;
        return p;
    };
    int*      gcnt   = (int*)     carve((size_t)NB * 4);
    int*      bptr   = (int*)     carve((size_t)(NB + 1) * 4);
    int*      gcur   = (int*)     carve((size_t)NB * 4);
    float*    dinv   = (float*)   carve((size_t)N * 4);
    unsigned* packed = (unsigned*)carve((size_t)E * 4);
    float*    bufA   = (float*)   carve((size_t)N * HID * 4);  // h1, then h2
    float*    bufB   = (float*)   carve((size_t)N * HID * 4);  // relu(agg1)
    (void)ws_size; (void)n_in;

    float* outp = (float*)d_out;

    // build bucket partition
    hipMemsetAsync(gcnt, 0, (size_t)NB * 4, stream);
    bucket_count_kernel<<<512, 256, 0, stream>>>(col, gcnt, E, NB);
    bucket_scan_kernel<<<1, 64, 0, stream>>>(gcnt, bptr, gcur, NB);
    partition_kernel<<<(E + CHUNK - 1) / CHUNK, 512, 0, stream>>>(row, col, gcur, packed, E, NB);
    bucket_deg_kernel<<<NB, 256, 0, stream>>>(bptr, packed, dinv, N, NB);

    // layer 1
    dense_kernel<128, 32><<<2048, 256, 0, stream>>>(x, W1, bufA, N);
    bucket_agg_kernel<32, true><<<NB, 512, 0, stream>>>(bptr, packed, dinv, bufA, b1, bufB, N, NB);
    // layer 2
    dense_kernel<32, 16><<<2048, 256, 0, stream>>>(bufB, W2, bufA, N);
    bucket_agg_kernel<16, false><<<NB, 512, 0, stream>>>(bptr, packed, dinv, bufA, b2, outp, N, NB);

    if (out_size > N * OC)
        tail_kernel<<<1, 64, 0, stream>>>(outp, N * OC);
}

// Round 5
// 1338.084 us; speedup vs baseline: 1.0084x; 1.0084x over previous
//
#include <hip/hip_runtime.h>

// GCN 2-layer forward, fp32. Bucket-partitioned pull aggregation.
// Round-4 evidence: bucket_agg was latency-bound (BW 3%, VALU 5%, 0 LDS
// conflicts) — one dependent chain packed->dinv->h per iteration, unroll 2.
// Round-5 fix: (a) prescale h by dinv in the dense epilogue so the per-edge
// chain is packed->h only; (b) explicit 8-deep batched loads for MLP.

#define WAVE 64
#define BNODES 128        // target nodes per bucket (7 bits local col)
#define NBMAX 1024        // max buckets supported (N <= 131072)
#define CHUNK 8192        // edges per partition block

// ---- bucket count: global histogram of col>>7 ----
__global__ void bucket_count_kernel(const int* __restrict__ col, int* __restrict__ gcnt,
                                    int E, int nb) {
    __shared__ int h[NBMAX];
    for (int i = threadIdx.x; i < nb; i += blockDim.x) h[i] = 0;
    __syncthreads();
    for (int e = blockIdx.x * blockDim.x + threadIdx.x; e < E; e += gridDim.x * blockDim.x)
        atomicAdd(&h[col[e] >> 7], 1);
    __syncthreads();
    for (int i = threadIdx.x; i < nb; i += blockDim.x)
        if (h[i]) atomicAdd(&gcnt[i], h[i]);
}

// ---- exclusive scan of bucket counts -> bucket_ptr[nb+1], init gcursor ----
__global__ void bucket_scan_kernel(const int* __restrict__ cnt, int* __restrict__ bptr,
                                   int* __restrict__ gcur, int nb) {
    int lane = threadIdx.x;  // single wave of 64
    int carry = 0;
    for (int base = 0; base < nb; base += WAVE) {
        int i = base + lane;
        int orig = (i < nb) ? cnt[i] : 0;
        int v = orig;
#pragma unroll
        for (int off = 1; off < WAVE; off <<= 1) {
            int t = __shfl_up(v, off, WAVE);
            if (lane >= off) v += t;
        }
        if (i < nb) { bptr[i] = carry + v - orig; gcur[i] = carry + v - orig; }
        carry += __shfl(v, WAVE - 1, WAVE);
    }
    if (lane == 0) bptr[nb] = carry;
}

// ---- partition: LDS-binned scatter of packed (src<<7 | local_col) ----
__global__ void __launch_bounds__(512)
partition_kernel(const int* __restrict__ row, const int* __restrict__ col,
                 int* __restrict__ gcursor, unsigned* __restrict__ packed,
                 int E, int nb) {
    __shared__ int hist[NBMAX], excl[NBMAX], cursor[NBMAX], baseoff[NBMAX];
    __shared__ unsigned stage[CHUNK];
    int chunk0 = blockIdx.x * CHUNK;
    int cn = E - chunk0; if (cn > CHUNK) cn = CHUNK;
    for (int i = threadIdx.x; i < nb; i += blockDim.x) hist[i] = 0;
    __syncthreads();
    for (int i = threadIdx.x; i < cn; i += blockDim.x)
        atomicAdd(&hist[col[chunk0 + i] >> 7], 1);
    __syncthreads();
    if (threadIdx.x < WAVE) {
        int lane = threadIdx.x, carry = 0;
        for (int base = 0; base < nb; base += WAVE) {
            int i = base + lane;
            int orig = (i < nb) ? hist[i] : 0;
            int v = orig;
#pragma unroll
            for (int off = 1; off < WAVE; off <<= 1) {
                int t = __shfl_up(v, off, WAVE);
                if (lane >= off) v += t;
            }
            if (i < nb) { excl[i] = carry + v - orig; cursor[i] = carry + v - orig; }
            carry += __shfl(v, WAVE - 1, WAVE);
        }
    }
    __syncthreads();
    for (int b = threadIdx.x; b < nb; b += blockDim.x) {
        int c = hist[b];
        baseoff[b] = c ? atomicAdd(&gcursor[b], c) : 0;
    }
    __syncthreads();
    for (int i = threadIdx.x; i < cn; i += blockDim.x) {
        int c = col[chunk0 + i], r = row[chunk0 + i];
        int b = c >> 7;
        int pos = atomicAdd(&cursor[b], 1);
        stage[pos] = ((unsigned)r << 7) | (unsigned)(c & (BNODES - 1));
    }
    __syncthreads();
    int wave = threadIdx.x >> 6, lane = threadIdx.x & 63, nw = blockDim.x >> 6;
    for (int b = wave; b < nb; b += nw) {
        int c = hist[b]; if (!c) continue;
        int s = excl[b], d = baseoff[b];
        for (int k = lane; k < c; k += WAVE) packed[d + k] = stage[s + k];
    }
}

// ---- per-bucket degree -> dinv ----
__global__ void bucket_deg_kernel(const int* __restrict__ bptr, const unsigned* __restrict__ packed,
                                  float* __restrict__ dinv, int n, int nb) {
    __shared__ int cnt[BNODES];
    int b = blockIdx.x;
    for (int i = threadIdx.x; i < BNODES; i += blockDim.x) cnt[i] = 0;
    __syncthreads();
    int start = bptr[b], end = bptr[b + 1];
    for (int k = start + threadIdx.x; k < end; k += blockDim.x)
        atomicAdd(&cnt[packed[k] & (BNODES - 1)], 1);
    __syncthreads();
    for (int i = threadIdx.x; i < BNODES; i += blockDim.x) {
        int node = b * BNODES + i;
        if (node < n) dinv[node] = cnt[i] ? rsqrtf((float)cnt[i]) : 0.f;
    }
}

// ---- dense: h[n,OUTC] = (x[n,INC] @ W) * dinv[n]  (dinv prescale fused) ----
template <int INC, int OUTC>
__global__ void dense_kernel(const float* __restrict__ x, const float* __restrict__ W,
                             const float* __restrict__ dinv, float* __restrict__ h, int n) {
    __shared__ float Wl[INC * OUTC];
    for (int i = threadIdx.x; i < INC * OUTC; i += blockDim.x) Wl[i] = W[i];
    __syncthreads();
    const int npb  = blockDim.x / OUTC;
    const int j    = threadIdx.x % OUTC;
    const int slot = threadIdx.x / OUTC;
    for (int node = blockIdx.x * npb + slot; node < n; node += gridDim.x * npb) {
        const float4* xr = (const float4*)(x + (size_t)node * INC);
        float acc = 0.f;
#pragma unroll
        for (int k4 = 0; k4 < INC / 4; ++k4) {
            float4 v = xr[k4];
            acc = fmaf(v.x, Wl[(k4 * 4 + 0) * OUTC + j], acc);
            acc = fmaf(v.y, Wl[(k4 * 4 + 1) * OUTC + j], acc);
            acc = fmaf(v.z, Wl[(k4 * 4 + 2) * OUTC + j], acc);
            acc = fmaf(v.w, Wl[(k4 * 4 + 3) * OUTC + j], acc);
        }
        h[(size_t)node * OUTC + j] = acc * dinv[node];
    }
}

// ---- bucket aggregate: LDS fp32 tile, 8-deep batched gathers ----
template <int C, bool RELU>
__global__ void __launch_bounds__(512)
bucket_agg_kernel(const int* __restrict__ bptr, const unsigned* __restrict__ packed,
                  const float* __restrict__ dinv, const float* __restrict__ hs,
                  const float* __restrict__ bias, float* __restrict__ out,
                  int n, int nb) {
    __shared__ float acc[BNODES * C];
    __shared__ float dl[BNODES];
    __shared__ float bl[C];
    int b = blockIdx.x;
    int base_node = b * BNODES;
    for (int i = threadIdx.x; i < BNODES * C; i += blockDim.x) acc[i] = 0.f;
    for (int i = threadIdx.x; i < BNODES; i += blockDim.x) {
        int node = base_node + i;
        dl[i] = (node < n) ? dinv[node] : 0.f;
    }
    if (threadIdx.x < C) bl[threadIdx.x] = bias[threadIdx.x];
    __syncthreads();
    int start = bptr[b], end = bptr[b + 1];
    const int EPW = WAVE / C;                 // edges per wave-step
    const int nwaves = 512 / WAVE;            // 8
    const int step = nwaves * EPW;
    int wave = threadIdx.x >> 6;
    int lane = threadIdx.x & 63;
    int j  = lane & (C - 1);
    int eo = lane / C;

    int k = start + wave * EPW + eo;
    // main: 8 independent packed->h chains in flight
    for (; k + 7 * step < end; k += 8 * step) {
        float hv[8], w[8];
        int   lc8[8];
#pragma unroll
        for (int u = 0; u < 8; ++u) {
            unsigned p = packed[k + u * step];
            int lc  = p & (BNODES - 1);
            int src = p >> 7;
            lc8[u] = lc;
            w[u]   = dl[lc];
            hv[u]  = hs[(size_t)src * C + j];   // h prescaled by dinv[src]
        }
#pragma unroll
        for (int u = 0; u < 8; ++u)
            atomicAdd(&acc[lc8[u] * C + j], hv[u] * w[u]);
    }
    // tail
    for (; k < end; k += step) {
        unsigned p = packed[k];
        int lc  = p & (BNODES - 1);
        int src = p >> 7;
        atomicAdd(&acc[lc * C + j], hs[(size_t)src * C + j] * dl[lc]);
    }
    __syncthreads();
    for (int i = threadIdx.x; i < BNODES * C; i += blockDim.x) {
        int node = base_node + (i / C);
        if (node < n) {
            float v = acc[i] + bl[i & (C - 1)];
            if (RELU) v = v > 0.f ? v : 0.f;
            out[(size_t)base_node * C + i] = v;
        }
    }
}

__global__ void tail_kernel(float* __restrict__ out, int idx) {
    if (blockIdx.x == 0 && threadIdx.x == 0) out[idx] = 0.f;
}

extern "C" void kernel_launch(void* const* d_in, const int* in_sizes, int n_in,
                              void* d_out, int out_size, void* d_ws, size_t ws_size,
                              hipStream_t stream) {
    const float* x  = (const float*)d_in[0];
    const int*   ei = (const int*)d_in[1];    // harness converts int64 -> int32
    const float* W1 = (const float*)d_in[2];
    const float* b1 = (const float*)d_in[3];
    const float* W2 = (const float*)d_in[4];
    const float* b2 = (const float*)d_in[5];

    const int IN_C = 128, HID = 32, OC = 16;
    const int N = in_sizes[0] / IN_C;       // 100000
    const int E = in_sizes[1] / 2;          // 3200000
    const int* row = ei;
    const int* col = ei + E;
    const int NB = (N + BNODES - 1) / BNODES;   // 782

    char* base = (char*)d_ws;
    size_t off = 0;
    auto carve = [&](size_t bytes) -> char* {
        char* p = base + off;
        off = (off + bytes + 255) & ~(size_t)255;
        return p;
    };
    int*      gcnt   = (int*)     carve((size_t)NB * 4);
    int*      bptr   = (int*)     carve((size_t)(NB + 1) * 4);
    int*      gcur   = (int*)     carve((size_t)NB * 4);
    float*    dinv   = (float*)   carve((size_t)N * 4);
    unsigned* packed = (unsigned*)carve((size_t)E * 4);
    float*    bufA   = (float*)   carve((size_t)N * HID * 4);  // h1', then h2'
    float*    bufB   = (float*)   carve((size_t)N * HID * 4);  // relu(agg1)
    (void)ws_size; (void)n_in;

    float* outp = (float*)d_out;

    // build bucket partition + dinv
    hipMemsetAsync(gcnt, 0, (size_t)NB * 4, stream);
    bucket_count_kernel<<<512, 256, 0, stream>>>(col, gcnt, E, NB);
    bucket_scan_kernel<<<1, 64, 0, stream>>>(gcnt, bptr, gcur, NB);
    partition_kernel<<<(E + CHUNK - 1) / CHUNK, 512, 0, stream>>>(row, col, gcur, packed, E, NB);
    bucket_deg_kernel<<<NB, 256, 0, stream>>>(bptr, packed, dinv, N, NB);

    // layer 1: h1' = (x@W1)*dinv ; bufB = relu(agg(h1') + b1)
    dense_kernel<128, 32><<<2048, 256, 0, stream>>>(x, W1, dinv, bufA, N);
    bucket_agg_kernel<32, true><<<NB, 512, 0, stream>>>(bptr, packed, dinv, bufA, b1, bufB, N, NB);
    // layer 2: h2' = (bufB@W2)*dinv ; out = agg(h2') + b2
    dense_kernel<32, 16><<<2048, 256, 0, stream>>>(bufB, W2, dinv, bufA, N);
    bucket_agg_kernel<16, false><<<NB, 512, 0, stream>>>(bptr, packed, dinv, bufA, b2, outp, N, NB);

    if (out_size > N * OC)
        tail_kernel<<<1, 64, 0, stream>>>(outp, N * OC);
}

// Round 6
// 472.551 us; speedup vs baseline: 2.8553x; 2.8316x over previous
//
#include <hip/hip_runtime.h>

// GCN 2-layer forward, fp32. Two-pass MSD radix sort of edges by target node
// (pass1: 128-node buckets via coalesced LDS-staged partition; pass2:
// per-bucket LDS-histogram sort with scatter into the bucket's L2-resident
// 16 KB window), then pull-aggregation with PURE REGISTER accumulation.
// Round-5 evidence: C LDS-atomic RMWs per edge saturate the DS pipe
// (~4 cyc/lane-op, 102M lane-ops -> 677 us, insensitive to gather batching).
// This version has zero DS ops in the aggregation inner loop.

#define WAVE 64
#define BNODES 128        // target nodes per bucket (7 bits local col)
#define NBMAX 1024        // max buckets supported (N <= 131072)
#define CHUNK 8192        // edges per partition block

// ---- bucket count: global histogram of col>>7 ----
__global__ void bucket_count_kernel(const int* __restrict__ col, int* __restrict__ gcnt,
                                    int E, int nb) {
    __shared__ int h[NBMAX];
    for (int i = threadIdx.x; i < nb; i += blockDim.x) h[i] = 0;
    __syncthreads();
    for (int e = blockIdx.x * blockDim.x + threadIdx.x; e < E; e += gridDim.x * blockDim.x)
        atomicAdd(&h[col[e] >> 7], 1);
    __syncthreads();
    for (int i = threadIdx.x; i < nb; i += blockDim.x)
        if (h[i]) atomicAdd(&gcnt[i], h[i]);
}

// ---- exclusive scan of bucket counts -> bptr[nb+1], init gcursor ----
__global__ void bucket_scan_kernel(const int* __restrict__ cnt, int* __restrict__ bptr,
                                   int* __restrict__ gcur, int nb) {
    int lane = threadIdx.x;  // single wave
    int carry = 0;
    for (int base = 0; base < nb; base += WAVE) {
        int i = base + lane;
        int orig = (i < nb) ? cnt[i] : 0;
        int v = orig;
#pragma unroll
        for (int off = 1; off < WAVE; off <<= 1) {
            int t = __shfl_up(v, off, WAVE);
            if (lane >= off) v += t;
        }
        if (i < nb) { bptr[i] = carry + v - orig; gcur[i] = carry + v - orig; }
        carry += __shfl(v, WAVE - 1, WAVE);
    }
    if (lane == 0) bptr[nb] = carry;
}

// ---- pass 1: LDS-binned partition of packed (src<<7 | local_col) ----
__global__ void __launch_bounds__(512)
partition_kernel(const int* __restrict__ row, const int* __restrict__ col,
                 int* __restrict__ gcursor, unsigned* __restrict__ packed,
                 int E, int nb) {
    __shared__ int hist[NBMAX], excl[NBMAX], cursor[NBMAX], baseoff[NBMAX];
    __shared__ unsigned stage[CHUNK];
    int chunk0 = blockIdx.x * CHUNK;
    int cn = E - chunk0; if (cn > CHUNK) cn = CHUNK;
    for (int i = threadIdx.x; i < nb; i += blockDim.x) hist[i] = 0;
    __syncthreads();
    for (int i = threadIdx.x; i < cn; i += blockDim.x)
        atomicAdd(&hist[col[chunk0 + i] >> 7], 1);
    __syncthreads();
    if (threadIdx.x < WAVE) {
        int lane = threadIdx.x, carry = 0;
        for (int base = 0; base < nb; base += WAVE) {
            int i = base + lane;
            int orig = (i < nb) ? hist[i] : 0;
            int v = orig;
#pragma unroll
            for (int off = 1; off < WAVE; off <<= 1) {
                int t = __shfl_up(v, off, WAVE);
                if (lane >= off) v += t;
            }
            if (i < nb) { excl[i] = carry + v - orig; cursor[i] = carry + v - orig; }
            carry += __shfl(v, WAVE - 1, WAVE);
        }
    }
    __syncthreads();
    for (int b = threadIdx.x; b < nb; b += blockDim.x) {
        int c = hist[b];
        baseoff[b] = c ? atomicAdd(&gcursor[b], c) : 0;
    }
    __syncthreads();
    for (int i = threadIdx.x; i < cn; i += blockDim.x) {
        int c = col[chunk0 + i], r = row[chunk0 + i];
        int b = c >> 7;
        int pos = atomicAdd(&cursor[b], 1);
        stage[pos] = ((unsigned)r << 7) | (unsigned)(c & (BNODES - 1));
    }
    __syncthreads();
    int wave = threadIdx.x >> 6, lane = threadIdx.x & 63, nw = blockDim.x >> 6;
    for (int b = wave; b < nb; b += nw) {
        int c = hist[b]; if (!c) continue;
        int s = excl[b], d = baseoff[b];
        for (int k = lane; k < c; k += WAVE) packed[d + k] = stage[s + k];
    }
}

// ---- pass 2: per-bucket sort by local node; emits srcs (node-sorted),
//      rowptr, dinv. Scatter window is the bucket's own 16 KB (L2-held). ----
__global__ void sort_kernel(const int* __restrict__ bptr, const unsigned* __restrict__ packed,
                            int* __restrict__ srcs, int* __restrict__ rowptr,
                            float* __restrict__ dinv, int n, int nb, int E) {
    __shared__ int hist[BNODES], excl[BNODES], cur[BNODES];
    int b = blockIdx.x;
    int start = bptr[b], end = bptr[b + 1];
    for (int i = threadIdx.x; i < BNODES; i += blockDim.x) hist[i] = 0;
    __syncthreads();
    for (int k = start + threadIdx.x; k < end; k += blockDim.x)
        atomicAdd(&hist[packed[k] & (BNODES - 1)], 1);
    __syncthreads();
    if (threadIdx.x < WAVE) {
        int lane = threadIdx.x, carry = 0;
#pragma unroll
        for (int base = 0; base < BNODES; base += WAVE) {
            int i = base + lane;
            int orig = hist[i];
            int v = orig;
#pragma unroll
            for (int off = 1; off < WAVE; off <<= 1) {
                int t = __shfl_up(v, off, WAVE);
                if (lane >= off) v += t;
            }
            excl[i] = carry + v - orig;
            cur[i]  = carry + v - orig;
            carry += __shfl(v, WAVE - 1, WAVE);
        }
    }
    __syncthreads();
    for (int i = threadIdx.x; i < BNODES; i += blockDim.x) {
        int node = b * BNODES + i;
        if (node < n) {
            rowptr[node] = start + excl[i];
            dinv[node]   = hist[i] ? rsqrtf((float)hist[i]) : 0.f;
        }
    }
    if (b == nb - 1 && threadIdx.x == 0) rowptr[n] = E;
    __syncthreads();
    for (int k = start + threadIdx.x; k < end; k += blockDim.x) {
        unsigned p = packed[k];
        int lc = p & (BNODES - 1);
        int pos = atomicAdd(&cur[lc], 1);
        srcs[start + pos] = (int)(p >> 7);
    }
}

// ---- dense: h[n,OUTC] = (x[n,INC] @ W) * dinv[n]  (prescale fused) ----
template <int INC, int OUTC>
__global__ void dense_kernel(const float* __restrict__ x, const float* __restrict__ W,
                             const float* __restrict__ dinv, float* __restrict__ h, int n) {
    __shared__ float Wl[INC * OUTC];
    for (int i = threadIdx.x; i < INC * OUTC; i += blockDim.x) Wl[i] = W[i];
    __syncthreads();
    const int npb  = blockDim.x / OUTC;
    const int j    = threadIdx.x % OUTC;
    const int slot = threadIdx.x / OUTC;
    for (int node = blockIdx.x * npb + slot; node < n; node += gridDim.x * npb) {
        const float4* xr = (const float4*)(x + (size_t)node * INC);
        float acc = 0.f;
#pragma unroll
        for (int k4 = 0; k4 < INC / 4; ++k4) {
            float4 v = xr[k4];
            acc = fmaf(v.x, Wl[(k4 * 4 + 0) * OUTC + j], acc);
            acc = fmaf(v.y, Wl[(k4 * 4 + 1) * OUTC + j], acc);
            acc = fmaf(v.z, Wl[(k4 * 4 + 2) * OUTC + j], acc);
            acc = fmaf(v.w, Wl[(k4 * 4 + 3) * OUTC + j], acc);
        }
        h[(size_t)node * OUTC + j] = acc * dinv[node];
    }
}

// ---- aggregate: one wave per node, register accumulation, no DS ops.
//      out[v,j] = RELU?( dinv[v] * sum_k h'[srcs[k], j] + bias[j] ) ----
template <int C, bool RELU>
__global__ void csr_agg_kernel(const int* __restrict__ rowptr, const int* __restrict__ srcs,
                               const float* __restrict__ dinv, const float* __restrict__ hs,
                               const float* __restrict__ bias, float* __restrict__ out, int n) {
    const int EPW = WAVE / C;  // edges in flight per wave-step
    int node = (int)((blockIdx.x * (unsigned)blockDim.x + threadIdx.x) >> 6);
    int lane = threadIdx.x & 63;
    int j  = lane & (C - 1);
    int eo = lane / C;
    if (node >= n) return;
    int start = rowptr[node], end = rowptr[node + 1];
    float acc = 0.f;
    int k = start + eo;
    // 8 independent gathers in flight
    for (; k + 7 * EPW < end; k += 8 * EPW) {
        int s[8];
#pragma unroll
        for (int u = 0; u < 8; ++u) s[u] = srcs[k + u * EPW];
        float hv[8];
#pragma unroll
        for (int u = 0; u < 8; ++u) hv[u] = hs[(size_t)s[u] * C + j];
#pragma unroll
        for (int u = 0; u < 8; ++u) acc += hv[u];
    }
    for (; k < end; k += EPW)
        acc += hs[(size_t)srcs[k] * C + j];
#pragma unroll
    for (int off = C; off < WAVE; off <<= 1)
        acc += __shfl_xor(acc, off, WAVE);
    if (eo == 0) {
        float v = acc * dinv[node] + bias[j];
        if (RELU) v = v > 0.f ? v : 0.f;
        out[(size_t)node * C + j] = v;
    }
}

__global__ void tail_kernel(float* __restrict__ out, int idx) {
    if (blockIdx.x == 0 && threadIdx.x == 0) out[idx] = 0.f;
}

extern "C" void kernel_launch(void* const* d_in, const int* in_sizes, int n_in,
                              void* d_out, int out_size, void* d_ws, size_t ws_size,
                              hipStream_t stream) {
    const float* x  = (const float*)d_in[0];
    const int*   ei = (const int*)d_in[1];    // harness converts int64 -> int32
    const float* W1 = (const float*)d_in[2];
    const float* b1 = (const float*)d_in[3];
    const float* W2 = (const float*)d_in[4];
    const float* b2 = (const float*)d_in[5];

    const int IN_C = 128, HID = 32, OC = 16;
    const int N = in_sizes[0] / IN_C;       // 100000
    const int E = in_sizes[1] / 2;          // 3200000
    const int* row = ei;
    const int* col = ei + E;
    const int NB = (N + BNODES - 1) / BNODES;   // 782

    char* base = (char*)d_ws;
    size_t off = 0;
    auto carve = [&](size_t bytes) -> char* {
        char* p = base + off;
        off = (off + bytes + 255) & ~(size_t)255;
        return p;
    };
    int*      gcnt   = (int*)     carve((size_t)NB * 4);
    int*      bptr   = (int*)     carve((size_t)(NB + 1) * 4);
    int*      gcur   = (int*)     carve((size_t)NB * 4);
    int*      rowptr = (int*)     carve((size_t)(N + 1) * 4);
    float*    dinv   = (float*)   carve((size_t)N * 4);
    unsigned* packed = (unsigned*)carve((size_t)E * 4);
    int*      srcs   = (int*)     carve((size_t)E * 4);
    float*    bufA   = (float*)   carve((size_t)N * HID * 4);  // h1', then h2'
    float*    bufB   = (float*)   carve((size_t)N * HID * 4);  // relu(agg1)
    (void)ws_size; (void)n_in;

    float* outp = (float*)d_out;

    // build: 2-pass radix sort by target node + rowptr + dinv
    hipMemsetAsync(gcnt, 0, (size_t)NB * 4, stream);
    bucket_count_kernel<<<512, 256, 0, stream>>>(col, gcnt, E, NB);
    bucket_scan_kernel<<<1, 64, 0, stream>>>(gcnt, bptr, gcur, NB);
    partition_kernel<<<(E + CHUNK - 1) / CHUNK, 512, 0, stream>>>(row, col, gcur, packed, E, NB);
    sort_kernel<<<NB, 256, 0, stream>>>(bptr, packed, srcs, rowptr, dinv, N, NB, E);

    // layer 1: h1' = (x@W1)*dinv ; bufB = relu(dinv*agg(h1') + b1)
    dense_kernel<128, 32><<<2048, 256, 0, stream>>>(x, W1, dinv, bufA, N);
    {
        int npb = 256 / WAVE;  // 4 nodes per block
        csr_agg_kernel<32, true><<<(N + npb - 1) / npb, 256, 0, stream>>>(
            rowptr, srcs, dinv, bufA, b1, bufB, N);
    }
    // layer 2: h2' = (bufB@W2)*dinv ; out = dinv*agg(h2') + b2
    dense_kernel<32, 16><<<2048, 256, 0, stream>>>(bufB, W2, dinv, bufA, N);
    {
        int npb = 256 / WAVE;
        csr_agg_kernel<16, false><<<(N + npb - 1) / npb, 256, 0, stream>>>(
            rowptr, srcs, dinv, bufA, b2, outp, N);
    }
    if (out_size > N * OC)
        tail_kernel<<<1, 64, 0, stream>>>(outp, N * OC);
}

// Round 7
// 446.570 us; speedup vs baseline: 3.0214x; 1.0582x over previous
//
#include <hip/hip_runtime.h>

// GCN 2-layer forward, fp32. Build: 2-pass MSD radix sort by target node.
// Aggregate: one wave per node, register accumulation (round 6: 1338->473us).
// Round-7: dense_kernel restructured — round-6 evidence showed it latency/
// issue-bound (VALU 8.4%, BW 535 GB/s, 141us vs ~30us floor): 32x-redundant
// x loads, 1 ds_read_b32 per FMA, single 128-deep FMA chain. Now: 4 outputs
// per thread (4 indep chains), W transposed in LDS w/ +4 pad (conflict-free
// ds_read_b128), 8x less x redundancy (full 128B/wave-load).

#define WAVE 64
#define BNODES 128        // target nodes per bucket (7 bits local col)
#define NBMAX 1024        // max buckets supported (N <= 131072)
#define CHUNK 8192        // edges per partition block

// ---- bucket count: global histogram of col>>7 ----
__global__ void bucket_count_kernel(const int* __restrict__ col, int* __restrict__ gcnt,
                                    int E, int nb) {
    __shared__ int h[NBMAX];
    for (int i = threadIdx.x; i < nb; i += blockDim.x) h[i] = 0;
    __syncthreads();
    for (int e = blockIdx.x * blockDim.x + threadIdx.x; e < E; e += gridDim.x * blockDim.x)
        atomicAdd(&h[col[e] >> 7], 1);
    __syncthreads();
    for (int i = threadIdx.x; i < nb; i += blockDim.x)
        if (h[i]) atomicAdd(&gcnt[i], h[i]);
}

// ---- exclusive scan of bucket counts -> bptr[nb+1], init gcursor ----
__global__ void bucket_scan_kernel(const int* __restrict__ cnt, int* __restrict__ bptr,
                                   int* __restrict__ gcur, int nb) {
    int lane = threadIdx.x;  // single wave
    int carry = 0;
    for (int base = 0; base < nb; base += WAVE) {
        int i = base + lane;
        int orig = (i < nb) ? cnt[i] : 0;
        int v = orig;
#pragma unroll
        for (int off = 1; off < WAVE; off <<= 1) {
            int t = __shfl_up(v, off, WAVE);
            if (lane >= off) v += t;
        }
        if (i < nb) { bptr[i] = carry + v - orig; gcur[i] = carry + v - orig; }
        carry += __shfl(v, WAVE - 1, WAVE);
    }
    if (lane == 0) bptr[nb] = carry;
}

// ---- pass 1: LDS-binned partition of packed (src<<7 | local_col) ----
__global__ void __launch_bounds__(512)
partition_kernel(const int* __restrict__ row, const int* __restrict__ col,
                 int* __restrict__ gcursor, unsigned* __restrict__ packed,
                 int E, int nb) {
    __shared__ int hist[NBMAX], excl[NBMAX], cursor[NBMAX], baseoff[NBMAX];
    __shared__ unsigned stage[CHUNK];
    int chunk0 = blockIdx.x * CHUNK;
    int cn = E - chunk0; if (cn > CHUNK) cn = CHUNK;
    for (int i = threadIdx.x; i < nb; i += blockDim.x) hist[i] = 0;
    __syncthreads();
    for (int i = threadIdx.x; i < cn; i += blockDim.x)
        atomicAdd(&hist[col[chunk0 + i] >> 7], 1);
    __syncthreads();
    if (threadIdx.x < WAVE) {
        int lane = threadIdx.x, carry = 0;
        for (int base = 0; base < nb; base += WAVE) {
            int i = base + lane;
            int orig = (i < nb) ? hist[i] : 0;
            int v = orig;
#pragma unroll
            for (int off = 1; off < WAVE; off <<= 1) {
                int t = __shfl_up(v, off, WAVE);
                if (lane >= off) v += t;
            }
            if (i < nb) { excl[i] = carry + v - orig; cursor[i] = carry + v - orig; }
            carry += __shfl(v, WAVE - 1, WAVE);
        }
    }
    __syncthreads();
    for (int b = threadIdx.x; b < nb; b += blockDim.x) {
        int c = hist[b];
        baseoff[b] = c ? atomicAdd(&gcursor[b], c) : 0;
    }
    __syncthreads();
    for (int i = threadIdx.x; i < cn; i += blockDim.x) {
        int c = col[chunk0 + i], r = row[chunk0 + i];
        int b = c >> 7;
        int pos = atomicAdd(&cursor[b], 1);
        stage[pos] = ((unsigned)r << 7) | (unsigned)(c & (BNODES - 1));
    }
    __syncthreads();
    int wave = threadIdx.x >> 6, lane = threadIdx.x & 63, nw = blockDim.x >> 6;
    for (int b = wave; b < nb; b += nw) {
        int c = hist[b]; if (!c) continue;
        int s = excl[b], d = baseoff[b];
        for (int k = lane; k < c; k += WAVE) packed[d + k] = stage[s + k];
    }
}

// ---- pass 2: per-bucket sort by local node -> srcs, rowptr, dinv ----
__global__ void sort_kernel(const int* __restrict__ bptr, const unsigned* __restrict__ packed,
                            int* __restrict__ srcs, int* __restrict__ rowptr,
                            float* __restrict__ dinv, int n, int nb, int E) {
    __shared__ int hist[BNODES], excl[BNODES], cur[BNODES];
    int b = blockIdx.x;
    int start = bptr[b], end = bptr[b + 1];
    for (int i = threadIdx.x; i < BNODES; i += blockDim.x) hist[i] = 0;
    __syncthreads();
    for (int k = start + threadIdx.x; k < end; k += blockDim.x)
        atomicAdd(&hist[packed[k] & (BNODES - 1)], 1);
    __syncthreads();
    if (threadIdx.x < WAVE) {
        int lane = threadIdx.x, carry = 0;
#pragma unroll
        for (int base = 0; base < BNODES; base += WAVE) {
            int i = base + lane;
            int orig = hist[i];
            int v = orig;
#pragma unroll
            for (int off = 1; off < WAVE; off <<= 1) {
                int t = __shfl_up(v, off, WAVE);
                if (lane >= off) v += t;
            }
            excl[i] = carry + v - orig;
            cur[i]  = carry + v - orig;
            carry += __shfl(v, WAVE - 1, WAVE);
        }
    }
    __syncthreads();
    for (int i = threadIdx.x; i < BNODES; i += blockDim.x) {
        int node = b * BNODES + i;
        if (node < n) {
            rowptr[node] = start + excl[i];
            dinv[node]   = hist[i] ? rsqrtf((float)hist[i]) : 0.f;
        }
    }
    if (b == nb - 1 && threadIdx.x == 0) rowptr[n] = E;
    __syncthreads();
    for (int k = start + threadIdx.x; k < end; k += blockDim.x) {
        unsigned p = packed[k];
        int lc = p & (BNODES - 1);
        int pos = atomicAdd(&cur[lc], 1);
        srcs[start + pos] = (int)(p >> 7);
    }
}

// ---- dense: h[n,OUTC] = (x[n,INC] @ W) * dinv[n]; 4 outputs per thread.
//      W transposed in LDS, row stride INC+4 -> conflict-free ds_read_b128:
//      bank(j0) = (4*j0 + 4*k4) % 32 spreads JT threads across banks. ----
template <int INC, int OUTC>
__global__ void __launch_bounds__(256)
dense_kernel(const float* __restrict__ x, const float* __restrict__ W,
             const float* __restrict__ dinv, float* __restrict__ h, int n) {
    const int JT   = OUTC / 4;    // threads per node
    const int LSTR = INC + 4;     // padded transposed stride (floats)
    __shared__ float Wt[OUTC * LSTR];
    for (int i = threadIdx.x; i < INC * OUTC; i += blockDim.x) {
        int k = i / OUTC, j = i % OUTC;
        Wt[j * LSTR + k] = W[i];
    }
    __syncthreads();
    const int npb  = 256 / JT;
    const int j0   = threadIdx.x % JT;
    const int slot = threadIdx.x / JT;
    for (int node = blockIdx.x * npb + slot; node < n; node += gridDim.x * npb) {
        const float4* xr = (const float4*)(x + (size_t)node * INC);
        float a0 = 0.f, a1 = 0.f, a2 = 0.f, a3 = 0.f;
#pragma unroll
        for (int k4 = 0; k4 < INC / 4; ++k4) {
            float4 v  = xr[k4];
            float4 w0 = *(const float4*)(Wt + (j0 + 0 * JT) * LSTR + 4 * k4);
            float4 w1 = *(const float4*)(Wt + (j0 + 1 * JT) * LSTR + 4 * k4);
            float4 w2 = *(const float4*)(Wt + (j0 + 2 * JT) * LSTR + 4 * k4);
            float4 w3 = *(const float4*)(Wt + (j0 + 3 * JT) * LSTR + 4 * k4);
            a0 = fmaf(v.x, w0.x, fmaf(v.y, w0.y, fmaf(v.z, w0.z, fmaf(v.w, w0.w, a0))));
            a1 = fmaf(v.x, w1.x, fmaf(v.y, w1.y, fmaf(v.z, w1.z, fmaf(v.w, w1.w, a1))));
            a2 = fmaf(v.x, w2.x, fmaf(v.y, w2.y, fmaf(v.z, w2.z, fmaf(v.w, w2.w, a2))));
            a3 = fmaf(v.x, w3.x, fmaf(v.y, w3.y, fmaf(v.z, w3.z, fmaf(v.w, w3.w, a3))));
        }
        float d = dinv[node];
        float* hr = h + (size_t)node * OUTC;
        hr[j0 + 0 * JT] = a0 * d;
        hr[j0 + 1 * JT] = a1 * d;
        hr[j0 + 2 * JT] = a2 * d;
        hr[j0 + 3 * JT] = a3 * d;
    }
}

// ---- aggregate: one wave per node, register accumulation, no DS ops ----
template <int C, bool RELU>
__global__ void csr_agg_kernel(const int* __restrict__ rowptr, const int* __restrict__ srcs,
                               const float* __restrict__ dinv, const float* __restrict__ hs,
                               const float* __restrict__ bias, float* __restrict__ out, int n) {
    const int EPW = WAVE / C;  // edges in flight per wave-step
    int node = (int)((blockIdx.x * (unsigned)blockDim.x + threadIdx.x) >> 6);
    int lane = threadIdx.x & 63;
    int j  = lane & (C - 1);
    int eo = lane / C;
    if (node >= n) return;
    int start = rowptr[node], end = rowptr[node + 1];
    float acc = 0.f;
    int k = start + eo;
    for (; k + 7 * EPW < end; k += 8 * EPW) {
        int s[8];
#pragma unroll
        for (int u = 0; u < 8; ++u) s[u] = srcs[k + u * EPW];
        float hv[8];
#pragma unroll
        for (int u = 0; u < 8; ++u) hv[u] = hs[(size_t)s[u] * C + j];
#pragma unroll
        for (int u = 0; u < 8; ++u) acc += hv[u];
    }
    for (; k < end; k += EPW)
        acc += hs[(size_t)srcs[k] * C + j];
#pragma unroll
    for (int off = C; off < WAVE; off <<= 1)
        acc += __shfl_xor(acc, off, WAVE);
    if (eo == 0) {
        float v = acc * dinv[node] + bias[j];
        if (RELU) v = v > 0.f ? v : 0.f;
        out[(size_t)node * C + j] = v;
    }
}

__global__ void tail_kernel(float* __restrict__ out, int idx) {
    if (blockIdx.x == 0 && threadIdx.x == 0) out[idx] = 0.f;
}

extern "C" void kernel_launch(void* const* d_in, const int* in_sizes, int n_in,
                              void* d_out, int out_size, void* d_ws, size_t ws_size,
                              hipStream_t stream) {
    const float* x  = (const float*)d_in[0];
    const int*   ei = (const int*)d_in[1];    // harness converts int64 -> int32
    const float* W1 = (const float*)d_in[2];
    const float* b1 = (const float*)d_in[3];
    const float* W2 = (const float*)d_in[4];
    const float* b2 = (const float*)d_in[5];

    const int IN_C = 128, HID = 32, OC = 16;
    const int N = in_sizes[0] / IN_C;       // 100000
    const int E = in_sizes[1] / 2;          // 3200000
    const int* row = ei;
    const int* col = ei + E;
    const int NB = (N + BNODES - 1) / BNODES;   // 782

    char* base = (char*)d_ws;
    size_t off = 0;
    auto carve = [&](size_t bytes) -> char* {
        char* p = base + off;
        off = (off + bytes + 255) & ~(size_t)255;
        return p;
    };
    int*      gcnt   = (int*)     carve((size_t)NB * 4);
    int*      bptr   = (int*)     carve((size_t)(NB + 1) * 4);
    int*      gcur   = (int*)     carve((size_t)NB * 4);
    int*      rowptr = (int*)     carve((size_t)(N + 1) * 4);
    float*    dinv   = (float*)   carve((size_t)N * 4);
    unsigned* packed = (unsigned*)carve((size_t)E * 4);
    int*      srcs   = (int*)     carve((size_t)E * 4);
    float*    bufA   = (float*)   carve((size_t)N * HID * 4);  // h1', then h2'
    float*    bufB   = (float*)   carve((size_t)N * HID * 4);  // relu(agg1)
    (void)ws_size; (void)n_in;

    float* outp = (float*)d_out;

    // build: 2-pass radix sort by target node + rowptr + dinv
    hipMemsetAsync(gcnt, 0, (size_t)NB * 4, stream);
    bucket_count_kernel<<<512, 256, 0, stream>>>(col, gcnt, E, NB);
    bucket_scan_kernel<<<1, 64, 0, stream>>>(gcnt, bptr, gcur, NB);
    partition_kernel<<<(E + CHUNK - 1) / CHUNK, 512, 0, stream>>>(row, col, gcur, packed, E, NB);
    sort_kernel<<<NB, 256, 0, stream>>>(bptr, packed, srcs, rowptr, dinv, N, NB, E);

    // layer 1: h1' = (x@W1)*dinv ; bufB = relu(dinv*agg(h1') + b1)
    {
        int npb = 256 / (32 / 4);  // 32 nodes per block
        dense_kernel<128, 32><<<(N + npb - 1) / npb, 256, 0, stream>>>(x, W1, dinv, bufA, N);
        int nppb = 256 / WAVE;     // 4 nodes per block
        csr_agg_kernel<32, true><<<(N + nppb - 1) / nppb, 256, 0, stream>>>(
            rowptr, srcs, dinv, bufA, b1, bufB, N);
    }
    // layer 2: h2' = (bufB@W2)*dinv ; out = dinv*agg(h2') + b2
    {
        int npb = 256 / (16 / 4);  // 64 nodes per block
        dense_kernel<32, 16><<<(N + npb - 1) / npb, 256, 0, stream>>>(bufB, W2, dinv, bufA, N);
        int nppb = 256 / WAVE;
        csr_agg_kernel<16, false><<<(N + nppb - 1) / nppb, 256, 0, stream>>>(
            rowptr, srcs, dinv, bufA, b2, outp, N);
    }
    if (out_size > N * OC)
        tail_kernel<<<1, 64, 0, stream>>>(outp, N * OC);
}

// Round 8
// 368.562 us; speedup vs baseline: 3.6609x; 1.2117x over previous
//
#include <hip/hip_runtime.h>

// GCN 2-layer forward, fp32. Build: 2-pass MSD radix sort by target node.
// Aggregate: one wave per node, register accumulation (round 6: 1338->473us).
// Round-8: dense_kernel register-tiled 2 nodes x 4 j per thread. Round-7
// evidence: full-unroll dense hit VGPR=168 -> occupancy 10.5% (latency
// unhidden); DS-inst count 16 b128/node. Now 8 b128/node, unroll 4,
// __launch_bounds__(256,4) caps VGPR at 128.

#define WAVE 64
#define BNODES 128        // target nodes per bucket (7 bits local col)
#define NBMAX 1024        // max buckets supported (N <= 131072)
#define CHUNK 8192        // edges per partition block

// ---- bucket count: global histogram of col>>7 ----
__global__ void bucket_count_kernel(const int* __restrict__ col, int* __restrict__ gcnt,
                                    int E, int nb) {
    __shared__ int h[NBMAX];
    for (int i = threadIdx.x; i < nb; i += blockDim.x) h[i] = 0;
    __syncthreads();
    for (int e = blockIdx.x * blockDim.x + threadIdx.x; e < E; e += gridDim.x * blockDim.x)
        atomicAdd(&h[col[e] >> 7], 1);
    __syncthreads();
    for (int i = threadIdx.x; i < nb; i += blockDim.x)
        if (h[i]) atomicAdd(&gcnt[i], h[i]);
}

// ---- exclusive scan of bucket counts -> bptr[nb+1], init gcursor ----
__global__ void bucket_scan_kernel(const int* __restrict__ cnt, int* __restrict__ bptr,
                                   int* __restrict__ gcur, int nb) {
    int lane = threadIdx.x;  // single wave
    int carry = 0;
    for (int base = 0; base < nb; base += WAVE) {
        int i = base + lane;
        int orig = (i < nb) ? cnt[i] : 0;
        int v = orig;
#pragma unroll
        for (int off = 1; off < WAVE; off <<= 1) {
            int t = __shfl_up(v, off, WAVE);
            if (lane >= off) v += t;
        }
        if (i < nb) { bptr[i] = carry + v - orig; gcur[i] = carry + v - orig; }
        carry += __shfl(v, WAVE - 1, WAVE);
    }
    if (lane == 0) bptr[nb] = carry;
}

// ---- pass 1: LDS-binned partition of packed (src<<7 | local_col) ----
__global__ void __launch_bounds__(512)
partition_kernel(const int* __restrict__ row, const int* __restrict__ col,
                 int* __restrict__ gcursor, unsigned* __restrict__ packed,
                 int E, int nb) {
    __shared__ int hist[NBMAX], excl[NBMAX], cursor[NBMAX], baseoff[NBMAX];
    __shared__ unsigned stage[CHUNK];
    int chunk0 = blockIdx.x * CHUNK;
    int cn = E - chunk0; if (cn > CHUNK) cn = CHUNK;
    for (int i = threadIdx.x; i < nb; i += blockDim.x) hist[i] = 0;
    __syncthreads();
    for (int i = threadIdx.x; i < cn; i += blockDim.x)
        atomicAdd(&hist[col[chunk0 + i] >> 7], 1);
    __syncthreads();
    if (threadIdx.x < WAVE) {
        int lane = threadIdx.x, carry = 0;
        for (int base = 0; base < nb; base += WAVE) {
            int i = base + lane;
            int orig = (i < nb) ? hist[i] : 0;
            int v = orig;
#pragma unroll
            for (int off = 1; off < WAVE; off <<= 1) {
                int t = __shfl_up(v, off, WAVE);
                if (lane >= off) v += t;
            }
            if (i < nb) { excl[i] = carry + v - orig; cursor[i] = carry + v - orig; }
            carry += __shfl(v, WAVE - 1, WAVE);
        }
    }
    __syncthreads();
    for (int b = threadIdx.x; b < nb; b += blockDim.x) {
        int c = hist[b];
        baseoff[b] = c ? atomicAdd(&gcursor[b], c) : 0;
    }
    __syncthreads();
    for (int i = threadIdx.x; i < cn; i += blockDim.x) {
        int c = col[chunk0 + i], r = row[chunk0 + i];
        int b = c >> 7;
        int pos = atomicAdd(&cursor[b], 1);
        stage[pos] = ((unsigned)r << 7) | (unsigned)(c & (BNODES - 1));
    }
    __syncthreads();
    int wave = threadIdx.x >> 6, lane = threadIdx.x & 63, nw = blockDim.x >> 6;
    for (int b = wave; b < nb; b += nw) {
        int c = hist[b]; if (!c) continue;
        int s = excl[b], d = baseoff[b];
        for (int k = lane; k < c; k += WAVE) packed[d + k] = stage[s + k];
    }
}

// ---- pass 2: per-bucket sort by local node -> srcs, rowptr, dinv ----
__global__ void sort_kernel(const int* __restrict__ bptr, const unsigned* __restrict__ packed,
                            int* __restrict__ srcs, int* __restrict__ rowptr,
                            float* __restrict__ dinv, int n, int nb, int E) {
    __shared__ int hist[BNODES], excl[BNODES], cur[BNODES];
    int b = blockIdx.x;
    int start = bptr[b], end = bptr[b + 1];
    for (int i = threadIdx.x; i < BNODES; i += blockDim.x) hist[i] = 0;
    __syncthreads();
    for (int k = start + threadIdx.x; k < end; k += blockDim.x)
        atomicAdd(&hist[packed[k] & (BNODES - 1)], 1);
    __syncthreads();
    if (threadIdx.x < WAVE) {
        int lane = threadIdx.x, carry = 0;
#pragma unroll
        for (int base = 0; base < BNODES; base += WAVE) {
            int i = base + lane;
            int orig = hist[i];
            int v = orig;
#pragma unroll
            for (int off = 1; off < WAVE; off <<= 1) {
                int t = __shfl_up(v, off, WAVE);
                if (lane >= off) v += t;
            }
            excl[i] = carry + v - orig;
            cur[i]  = carry + v - orig;
            carry += __shfl(v, WAVE - 1, WAVE);
        }
    }
    __syncthreads();
    for (int i = threadIdx.x; i < BNODES; i += blockDim.x) {
        int node = b * BNODES + i;
        if (node < n) {
            rowptr[node] = start + excl[i];
            dinv[node]   = hist[i] ? rsqrtf((float)hist[i]) : 0.f;
        }
    }
    if (b == nb - 1 && threadIdx.x == 0) rowptr[n] = E;
    __syncthreads();
    for (int k = start + threadIdx.x; k < end; k += blockDim.x) {
        unsigned p = packed[k];
        int lc = p & (BNODES - 1);
        int pos = atomicAdd(&cur[lc], 1);
        srcs[start + pos] = (int)(p >> 7);
    }
}

// ---- dense: h[n,OUTC] = (x[n,INC] @ W) * dinv[n].
//      Thread = 2 nodes x 4 j (j = jg + u*JT). W^T in LDS, stride INC+4:
//      b128 start bank = (4*jg + 4*k4) % 32, distinct across JT<=8 jg. ----
template <int INC, int OUTC, int JT>
__global__ void __launch_bounds__(256, 4)
dense_kernel(const float* __restrict__ x, const float* __restrict__ W,
             const float* __restrict__ dinv, float* __restrict__ h, int n) {
    const int LSTR = INC + 4;
    const int SP   = 256 / JT;     // node slots (pairs) per block
    const int NT   = SP * 2;       // nodes per block
    __shared__ float Wt[OUTC * LSTR];
    for (int i = threadIdx.x; i < INC * OUTC; i += 256) {
        int k = i / OUTC, j = i % OUTC;
        Wt[j * LSTR + k] = W[i];
    }
    __syncthreads();
    const int jg = threadIdx.x % JT;
    const int sp = threadIdx.x / JT;
    int base = blockIdx.x * NT;
    int n0 = base + sp;
    int n1 = base + sp + SP;
    int n0c = n0 < n ? n0 : n - 1;   // clamp reads, guard writes
    int n1c = n1 < n ? n1 : n - 1;
    const float4* xr0 = (const float4*)(x + (size_t)n0c * INC);
    const float4* xr1 = (const float4*)(x + (size_t)n1c * INC);
    float a[2][4] = {{0.f, 0.f, 0.f, 0.f}, {0.f, 0.f, 0.f, 0.f}};
#pragma unroll 4
    for (int k4 = 0; k4 < INC / 4; ++k4) {
        float4 v0 = xr0[k4];
        float4 v1 = xr1[k4];
#pragma unroll
        for (int u = 0; u < 4; ++u) {
            float4 w = *(const float4*)(Wt + (jg + u * JT) * LSTR + 4 * k4);
            a[0][u] = fmaf(v0.x, w.x, fmaf(v0.y, w.y, fmaf(v0.z, w.z, fmaf(v0.w, w.w, a[0][u]))));
            a[1][u] = fmaf(v1.x, w.x, fmaf(v1.y, w.y, fmaf(v1.z, w.z, fmaf(v1.w, w.w, a[1][u]))));
        }
    }
    if (n0 < n) {
        float d = dinv[n0];
        float* hr = h + (size_t)n0 * OUTC;
#pragma unroll
        for (int u = 0; u < 4; ++u) hr[jg + u * JT] = a[0][u] * d;
    }
    if (n1 < n) {
        float d = dinv[n1];
        float* hr = h + (size_t)n1 * OUTC;
#pragma unroll
        for (int u = 0; u < 4; ++u) hr[jg + u * JT] = a[1][u] * d;
    }
}

// ---- aggregate: one wave per node, register accumulation, no DS ops ----
template <int C, bool RELU>
__global__ void csr_agg_kernel(const int* __restrict__ rowptr, const int* __restrict__ srcs,
                               const float* __restrict__ dinv, const float* __restrict__ hs,
                               const float* __restrict__ bias, float* __restrict__ out, int n) {
    const int EPW = WAVE / C;  // edges in flight per wave-step
    int node = (int)((blockIdx.x * (unsigned)blockDim.x + threadIdx.x) >> 6);
    int lane = threadIdx.x & 63;
    int j  = lane & (C - 1);
    int eo = lane / C;
    if (node >= n) return;
    int start = rowptr[node], end = rowptr[node + 1];
    float acc = 0.f;
    int k = start + eo;
    for (; k + 7 * EPW < end; k += 8 * EPW) {
        int s[8];
#pragma unroll
        for (int u = 0; u < 8; ++u) s[u] = srcs[k + u * EPW];
        float hv[8];
#pragma unroll
        for (int u = 0; u < 8; ++u) hv[u] = hs[(size_t)s[u] * C + j];
#pragma unroll
        for (int u = 0; u < 8; ++u) acc += hv[u];
    }
    for (; k < end; k += EPW)
        acc += hs[(size_t)srcs[k] * C + j];
#pragma unroll
    for (int off = C; off < WAVE; off <<= 1)
        acc += __shfl_xor(acc, off, WAVE);
    if (eo == 0) {
        float v = acc * dinv[node] + bias[j];
        if (RELU) v = v > 0.f ? v : 0.f;
        out[(size_t)node * C + j] = v;
    }
}

__global__ void tail_kernel(float* __restrict__ out, int idx) {
    if (blockIdx.x == 0 && threadIdx.x == 0) out[idx] = 0.f;
}

extern "C" void kernel_launch(void* const* d_in, const int* in_sizes, int n_in,
                              void* d_out, int out_size, void* d_ws, size_t ws_size,
                              hipStream_t stream) {
    const float* x  = (const float*)d_in[0];
    const int*   ei = (const int*)d_in[1];    // harness converts int64 -> int32
    const float* W1 = (const float*)d_in[2];
    const float* b1 = (const float*)d_in[3];
    const float* W2 = (const float*)d_in[4];
    const float* b2 = (const float*)d_in[5];

    const int IN_C = 128, HID = 32, OC = 16;
    const int N = in_sizes[0] / IN_C;       // 100000
    const int E = in_sizes[1] / 2;          // 3200000
    const int* row = ei;
    const int* col = ei + E;
    const int NB = (N + BNODES - 1) / BNODES;   // 782

    char* base = (char*)d_ws;
    size_t off = 0;
    auto carve = [&](size_t bytes) -> char* {
        char* p = base + off;
        off = (off + bytes + 255) & ~(size_t)255;
        return p;
    };
    int*      gcnt   = (int*)     carve((size_t)NB * 4);
    int*      bptr   = (int*)     carve((size_t)(NB + 1) * 4);
    int*      gcur   = (int*)     carve((size_t)NB * 4);
    int*      rowptr = (int*)     carve((size_t)(N + 1) * 4);
    float*    dinv   = (float*)   carve((size_t)N * 4);
    unsigned* packed = (unsigned*)carve((size_t)E * 4);
    int*      srcs   = (int*)     carve((size_t)E * 4);
    float*    bufA   = (float*)   carve((size_t)N * HID * 4);  // h1', then h2'
    float*    bufB   = (float*)   carve((size_t)N * HID * 4);  // relu(agg1)
    (void)ws_size; (void)n_in;

    float* outp = (float*)d_out;

    // build: 2-pass radix sort by target node + rowptr + dinv
    hipMemsetAsync(gcnt, 0, (size_t)NB * 4, stream);
    bucket_count_kernel<<<512, 256, 0, stream>>>(col, gcnt, E, NB);
    bucket_scan_kernel<<<1, 64, 0, stream>>>(gcnt, bptr, gcur, NB);
    partition_kernel<<<(E + CHUNK - 1) / CHUNK, 512, 0, stream>>>(row, col, gcur, packed, E, NB);
    sort_kernel<<<NB, 256, 0, stream>>>(bptr, packed, srcs, rowptr, dinv, N, NB, E);

    // layer 1: h1' = (x@W1)*dinv ; bufB = relu(dinv*agg(h1') + b1)
    {
        const int NT = (256 / 8) * 2;  // 64 nodes per block
        dense_kernel<128, 32, 8><<<(N + NT - 1) / NT, 256, 0, stream>>>(x, W1, dinv, bufA, N);
        int nppb = 256 / WAVE;         // 4 nodes per block
        csr_agg_kernel<32, true><<<(N + nppb - 1) / nppb, 256, 0, stream>>>(
            rowptr, srcs, dinv, bufA, b1, bufB, N);
    }
    // layer 2: h2' = (bufB@W2)*dinv ; out = dinv*agg(h2') + b2
    {
        const int NT = (256 / 4) * 2;  // 128 nodes per block
        dense_kernel<32, 16, 4><<<(N + NT - 1) / NT, 256, 0, stream>>>(bufB, W2, dinv, bufA, N);
        int nppb = 256 / WAVE;
        csr_agg_kernel<16, false><<<(N + nppb - 1) / nppb, 256, 0, stream>>>(
            rowptr, srcs, dinv, bufA, b2, outp, N);
    }
    if (out_size > N * OC)
        tail_kernel<<<1, 64, 0, stream>>>(outp, N * OC);
}

// Round 9
// 323.658 us; speedup vs baseline: 4.1689x; 1.1387x over previous
//
#include <hip/hip_runtime.h>

// GCN 2-layer forward, fp32. Build: 2-pass MSD radix sort by target node
// (coarse 512-node buckets). Aggregate: one wave per node, register acc.
// Round-9: (a) agg inner loop fully predicated 8-deep (round-8 evidence:
// serial tail put half the edges through a dependent-chain path, VALU 27%);
// (b) radix coarsened 128->512 nodes/bucket: pass-1 flush runs 10->42 edges
// (was 87% idle lanes), pass-2 scatter window 65KB L2-resident.

#define WAVE 64
#define BN2 512           // nodes per bucket (9 bits local col)
#define NBMAX 256         // max coarse buckets (N <= 131072)
#define CHUNK 8192        // edges per partition block

// ---- bucket count: global histogram of col>>9 ----
__global__ void bucket_count_kernel(const int* __restrict__ col, int* __restrict__ gcnt,
                                    int E, int nb) {
    __shared__ int h[NBMAX];
    for (int i = threadIdx.x; i < nb; i += blockDim.x) h[i] = 0;
    __syncthreads();
    for (int e = blockIdx.x * blockDim.x + threadIdx.x; e < E; e += gridDim.x * blockDim.x)
        atomicAdd(&h[col[e] >> 9], 1);
    __syncthreads();
    for (int i = threadIdx.x; i < nb; i += blockDim.x)
        if (h[i]) atomicAdd(&gcnt[i], h[i]);
}

// ---- exclusive scan of bucket counts -> bptr[nb+1], init gcursor ----
__global__ void bucket_scan_kernel(const int* __restrict__ cnt, int* __restrict__ bptr,
                                   int* __restrict__ gcur, int nb) {
    int lane = threadIdx.x;  // single wave
    int carry = 0;
    for (int base = 0; base < nb; base += WAVE) {
        int i = base + lane;
        int orig = (i < nb) ? cnt[i] : 0;
        int v = orig;
#pragma unroll
        for (int off = 1; off < WAVE; off <<= 1) {
            int t = __shfl_up(v, off, WAVE);
            if (lane >= off) v += t;
        }
        if (i < nb) { bptr[i] = carry + v - orig; gcur[i] = carry + v - orig; }
        carry += __shfl(v, WAVE - 1, WAVE);
    }
    if (lane == 0) bptr[nb] = carry;
}

// ---- pass 1: LDS-binned partition of packed (src<<9 | local_col) ----
__global__ void __launch_bounds__(512)
partition_kernel(const int* __restrict__ row, const int* __restrict__ col,
                 int* __restrict__ gcursor, unsigned* __restrict__ packed,
                 int E, int nb) {
    __shared__ int hist[NBMAX], excl[NBMAX], cursor[NBMAX], baseoff[NBMAX];
    __shared__ unsigned stage[CHUNK];
    int chunk0 = blockIdx.x * CHUNK;
    int cn = E - chunk0; if (cn > CHUNK) cn = CHUNK;
    for (int i = threadIdx.x; i < nb; i += blockDim.x) hist[i] = 0;
    __syncthreads();
    for (int i = threadIdx.x; i < cn; i += blockDim.x)
        atomicAdd(&hist[col[chunk0 + i] >> 9], 1);
    __syncthreads();
    if (threadIdx.x < WAVE) {
        int lane = threadIdx.x, carry = 0;
        for (int base = 0; base < nb; base += WAVE) {
            int i = base + lane;
            int orig = (i < nb) ? hist[i] : 0;
            int v = orig;
#pragma unroll
            for (int off = 1; off < WAVE; off <<= 1) {
                int t = __shfl_up(v, off, WAVE);
                if (lane >= off) v += t;
            }
            if (i < nb) { excl[i] = carry + v - orig; cursor[i] = carry + v - orig; }
            carry += __shfl(v, WAVE - 1, WAVE);
        }
    }
    __syncthreads();
    for (int b = threadIdx.x; b < nb; b += blockDim.x) {
        int c = hist[b];
        baseoff[b] = c ? atomicAdd(&gcursor[b], c) : 0;
    }
    __syncthreads();
    for (int i = threadIdx.x; i < cn; i += blockDim.x) {
        int c = col[chunk0 + i], r = row[chunk0 + i];
        int b = c >> 9;
        int pos = atomicAdd(&cursor[b], 1);
        stage[pos] = ((unsigned)r << 9) | (unsigned)(c & (BN2 - 1));
    }
    __syncthreads();
    int wave = threadIdx.x >> 6, lane = threadIdx.x & 63, nw = blockDim.x >> 6;
    for (int b = wave; b < nb; b += nw) {
        int c = hist[b]; if (!c) continue;
        int s = excl[b], d = baseoff[b];
        for (int k = lane; k < c; k += WAVE) packed[d + k] = stage[s + k];
    }
}

// ---- pass 2: per-bucket sort by local node -> srcs, rowptr, dinv ----
__global__ void __launch_bounds__(256)
sort_kernel(const int* __restrict__ bptr, const unsigned* __restrict__ packed,
            int* __restrict__ srcs, int* __restrict__ rowptr,
            float* __restrict__ dinv, int n, int nb, int E) {
    __shared__ int hist[BN2], excl[BN2], cur[BN2];
    int b = blockIdx.x;
    int start = bptr[b], end = bptr[b + 1];
    for (int i = threadIdx.x; i < BN2; i += blockDim.x) hist[i] = 0;
    __syncthreads();
    for (int k = start + threadIdx.x; k < end; k += blockDim.x)
        atomicAdd(&hist[packed[k] & (BN2 - 1)], 1);
    __syncthreads();
    if (threadIdx.x < WAVE) {
        int lane = threadIdx.x, carry = 0;
#pragma unroll
        for (int base = 0; base < BN2; base += WAVE) {
            int i = base + lane;
            int orig = hist[i];
            int v = orig;
#pragma unroll
            for (int off = 1; off < WAVE; off <<= 1) {
                int t = __shfl_up(v, off, WAVE);
                if (lane >= off) v += t;
            }
            excl[i] = carry + v - orig;
            cur[i]  = carry + v - orig;
            carry += __shfl(v, WAVE - 1, WAVE);
        }
    }
    __syncthreads();
    for (int i = threadIdx.x; i < BN2; i += blockDim.x) {
        int node = b * BN2 + i;
        if (node < n) {
            rowptr[node] = start + excl[i];
            dinv[node]   = hist[i] ? rsqrtf((float)hist[i]) : 0.f;
        }
    }
    if (b == nb - 1 && threadIdx.x == 0) rowptr[n] = E;
    __syncthreads();
    for (int k = start + threadIdx.x; k < end; k += blockDim.x) {
        unsigned p = packed[k];
        int lc = p & (BN2 - 1);
        int pos = atomicAdd(&cur[lc], 1);
        srcs[start + pos] = (int)(p >> 9);
    }
}

// ---- dense: h[n,OUTC] = (x[n,INC] @ W) * dinv[n].
//      Thread = 2 nodes x 4 j. W^T in LDS, stride INC+4 (conflict-free). ----
template <int INC, int OUTC, int JT>
__global__ void __launch_bounds__(256, 4)
dense_kernel(const float* __restrict__ x, const float* __restrict__ W,
             const float* __restrict__ dinv, float* __restrict__ h, int n) {
    const int LSTR = INC + 4;
    const int SP   = 256 / JT;     // node slots (pairs) per block
    const int NT   = SP * 2;       // nodes per block
    __shared__ float Wt[OUTC * LSTR];
    for (int i = threadIdx.x; i < INC * OUTC; i += 256) {
        int k = i / OUTC, j = i % OUTC;
        Wt[j * LSTR + k] = W[i];
    }
    __syncthreads();
    const int jg = threadIdx.x % JT;
    const int sp = threadIdx.x / JT;
    int base = blockIdx.x * NT;
    int n0 = base + sp;
    int n1 = base + sp + SP;
    int n0c = n0 < n ? n0 : n - 1;   // clamp reads, guard writes
    int n1c = n1 < n ? n1 : n - 1;
    const float4* xr0 = (const float4*)(x + (size_t)n0c * INC);
    const float4* xr1 = (const float4*)(x + (size_t)n1c * INC);
    float a[2][4] = {{0.f, 0.f, 0.f, 0.f}, {0.f, 0.f, 0.f, 0.f}};
#pragma unroll 4
    for (int k4 = 0; k4 < INC / 4; ++k4) {
        float4 v0 = xr0[k4];
        float4 v1 = xr1[k4];
#pragma unroll
        for (int u = 0; u < 4; ++u) {
            float4 w = *(const float4*)(Wt + (jg + u * JT) * LSTR + 4 * k4);
            a[0][u] = fmaf(v0.x, w.x, fmaf(v0.y, w.y, fmaf(v0.z, w.z, fmaf(v0.w, w.w, a[0][u]))));
            a[1][u] = fmaf(v1.x, w.x, fmaf(v1.y, w.y, fmaf(v1.z, w.z, fmaf(v1.w, w.w, a[1][u]))));
        }
    }
    if (n0 < n) {
        float d = dinv[n0];
        float* hr = h + (size_t)n0 * OUTC;
#pragma unroll
        for (int u = 0; u < 4; ++u) hr[jg + u * JT] = a[0][u] * d;
    }
    if (n1 < n) {
        float d = dinv[n1];
        float* hr = h + (size_t)n1 * OUTC;
#pragma unroll
        for (int u = 0; u < 4; ++u) hr[jg + u * JT] = a[1][u] * d;
    }
}

// ---- aggregate: one wave per node, register acc, fully predicated 8-deep ----
template <int C, bool RELU>
__global__ void csr_agg_kernel(const int* __restrict__ rowptr, const int* __restrict__ srcs,
                               const float* __restrict__ dinv, const float* __restrict__ hs,
                               const float* __restrict__ bias, float* __restrict__ out, int n) {
    const int EPW = WAVE / C;  // edges in flight per wave-step
    int node = (int)((blockIdx.x * (unsigned)blockDim.x + threadIdx.x) >> 6);
    int lane = threadIdx.x & 63;
    int j  = lane & (C - 1);
    int eo = lane / C;
    if (node >= n) return;
    int start = rowptr[node], end = rowptr[node + 1];
    float acc = 0.f;
    // predicated 8-deep batches: clamped index loads (independent), masked acc
    for (int k = start + eo; k < end; k += 8 * EPW) {
        int idx[8];
        float hv[8];
#pragma unroll
        for (int u = 0; u < 8; ++u) {
            int t = k + u * EPW;
            idx[u] = t;
            int cl = t < end ? t : end - 1;
            hv[u] = hs[(size_t)srcs[cl] * C + j];
        }
#pragma unroll
        for (int u = 0; u < 8; ++u)
            acc += (idx[u] < end) ? hv[u] : 0.f;
    }
#pragma unroll
    for (int off = C; off < WAVE; off <<= 1)
        acc += __shfl_xor(acc, off, WAVE);
    if (eo == 0) {
        float v = acc * dinv[node] + bias[j];
        if (RELU) v = v > 0.f ? v : 0.f;
        out[(size_t)node * C + j] = v;
    }
}

__global__ void tail_kernel(float* __restrict__ out, int idx) {
    if (blockIdx.x == 0 && threadIdx.x == 0) out[idx] = 0.f;
}

extern "C" void kernel_launch(void* const* d_in, const int* in_sizes, int n_in,
                              void* d_out, int out_size, void* d_ws, size_t ws_size,
                              hipStream_t stream) {
    const float* x  = (const float*)d_in[0];
    const int*   ei = (const int*)d_in[1];    // harness converts int64 -> int32
    const float* W1 = (const float*)d_in[2];
    const float* b1 = (const float*)d_in[3];
    const float* W2 = (const float*)d_in[4];
    const float* b2 = (const float*)d_in[5];

    const int IN_C = 128, HID = 32, OC = 16;
    const int N = in_sizes[0] / IN_C;       // 100000
    const int E = in_sizes[1] / 2;          // 3200000
    const int* row = ei;
    const int* col = ei + E;
    const int NB = (N + BN2 - 1) / BN2;     // 196 coarse buckets

    char* base = (char*)d_ws;
    size_t off = 0;
    auto carve = [&](size_t bytes) -> char* {
        char* p = base + off;
        off = (off + bytes + 255) & ~(size_t)255;
        return p;
    };
    int*      gcnt   = (int*)     carve((size_t)NB * 4);
    int*      bptr   = (int*)     carve((size_t)(NB + 1) * 4);
    int*      gcur   = (int*)     carve((size_t)NB * 4);
    int*      rowptr = (int*)     carve((size_t)(N + 1) * 4);
    float*    dinv   = (float*)   carve((size_t)N * 4);
    unsigned* packed = (unsigned*)carve((size_t)E * 4);
    int*      srcs   = (int*)     carve((size_t)E * 4);
    float*    bufA   = (float*)   carve((size_t)N * HID * 4);  // h1', then h2'
    float*    bufB   = (float*)   carve((size_t)N * HID * 4);  // relu(agg1)
    (void)ws_size; (void)n_in;

    float* outp = (float*)d_out;

    // build: 2-pass coarse radix sort by target node + rowptr + dinv
    hipMemsetAsync(gcnt, 0, (size_t)NB * 4, stream);
    bucket_count_kernel<<<512, 256, 0, stream>>>(col, gcnt, E, NB);
    bucket_scan_kernel<<<1, 64, 0, stream>>>(gcnt, bptr, gcur, NB);
    partition_kernel<<<(E + CHUNK - 1) / CHUNK, 512, 0, stream>>>(row, col, gcur, packed, E, NB);
    sort_kernel<<<NB, 256, 0, stream>>>(bptr, packed, srcs, rowptr, dinv, N, NB, E);

    // layer 1: h1' = (x@W1)*dinv ; bufB = relu(dinv*agg(h1') + b1)
    {
        const int NT = (256 / 8) * 2;  // 64 nodes per block
        dense_kernel<128, 32, 8><<<(N + NT - 1) / NT, 256, 0, stream>>>(x, W1, dinv, bufA, N);
        int nppb = 256 / WAVE;         // 4 nodes per block
        csr_agg_kernel<32, true><<<(N + nppb - 1) / nppb, 256, 0, stream>>>(
            rowptr, srcs, dinv, bufA, b1, bufB, N);
    }
    // layer 2: h2' = (bufB@W2)*dinv ; out = dinv*agg(h2') + b2
    {
        const int NT = (256 / 4) * 2;  // 128 nodes per block
        dense_kernel<32, 16, 4><<<(N + NT - 1) / NT, 256, 0, stream>>>(bufB, W2, dinv, bufA, N);
        int nppb = 256 / WAVE;
        csr_agg_kernel<16, false><<<(N + nppb - 1) / nppb, 256, 0, stream>>>(
            rowptr, srcs, dinv, bufA, b2, outp, N);
    }
    if (out_size > N * OC)
        tail_kernel<<<1, 64, 0, stream>>>(outp, N * OC);
}